// Round 11
// baseline (328.094 us; speedup 1.0000x reference)
//
#include <hip/hip_runtime.h>
#include <math.h>

#define N_SRC 16384
#define M_REF 16384
#define DEMB  256
#define KNN_K 16
#define CAP   128
#define NC    32
#define GB    4.25f
#define CH    0.265625f        // 17/64, exact in fp32
#define NCELLS (NC * NC * NC)
#define KNNB   (N_SRC / 16)    // 1024 knn blocks (4 waves x 4 srcs)
#define QB     (N_SRC / 16)    // 1024 q blocks

__device__ __forceinline__ int cell_of(float x) {
    int c = (int)floorf((x + GB) * (1.0f / CH));
    return min(max(c, 0), NC - 1);
}

// ---------------- K1: zero both cursors + build W_sym ----------------
__global__ void __launch_bounds__(256) setup_kernel(int* __restrict__ rcur,
                                                    int* __restrict__ scur,
                                                    const float* __restrict__ W,
                                                    float* __restrict__ wsym) {
    int b = blockIdx.x, t = threadIdx.x;
    if (b < 128) {
        rcur[b * 256 + t] = 0;
    } else if (b < 256) {
        scur[(b - 128) * 256 + t] = 0;
    } else {
        int i = b - 256, j = t;
        float a = (j >= i) ? W[i * DEMB + j] : 0.f;
        float c = (i >= j) ? W[j * DEMB + i] : 0.f;
        wsym[i * DEMB + j] = a + c;
    }
}

// ---------------- K2: histograms (ref blocks 0..63, src blocks 64..127) ----------------
__global__ void __launch_bounds__(256) hist_kernel(const float* __restrict__ rp,
                                                   const float* __restrict__ sp,
                                                   int* __restrict__ rcur,
                                                   int* __restrict__ scur) {
    int b = blockIdx.x, t = threadIdx.x;
    const float* p = (b < 64) ? rp : sp;
    int* cur = (b < 64) ? rcur : scur;
    int i = (b & 63) * 256 + t;
    int cx = cell_of(p[i * 3 + 0]);
    int cy = cell_of(p[i * 3 + 1]);
    int cz = cell_of(p[i * 3 + 2]);
    atomicAdd(&cur[(cz * NC + cy) * NC + cx], 1);
}

// ---------------- K3: exclusive scans (block 0 ref, block 1 src) ----------------
__global__ void __launch_bounds__(1024) scan_kernel(int* __restrict__ rcur, int* __restrict__ rcs,
                                                    int* __restrict__ scur, int* __restrict__ scs) {
    int* cur = blockIdx.x ? scur : rcur;
    int* cs  = blockIdx.x ? scs  : rcs;
    __shared__ int part[1024];
    int t = threadIdx.x;
    int loc[32]; int s = 0;
    #pragma unroll
    for (int i = 0; i < 32; ++i) { loc[i] = s; s += cur[t * 32 + i]; }
    part[t] = s;
    __syncthreads();
    for (int off = 1; off < 1024; off <<= 1) {
        int add = (t >= off) ? part[t - off] : 0;
        __syncthreads();
        part[t] += add;
        __syncthreads();
    }
    int ex = part[t] - s;
    #pragma unroll
    for (int i = 0; i < 32; ++i) {
        cs[t * 32 + i]  = ex + loc[i];
        cur[t * 32 + i] = ex + loc[i];
    }
    if (t == 1023) cs[NCELLS] = part[1023];
}

// ---------------- K4: scatter into CSR order (ref blocks 0..63, src 64..127) ----------
__global__ void __launch_bounds__(256) scatter_kernel(const float* __restrict__ rp,
        const float* __restrict__ sp, int* __restrict__ rcur, int* __restrict__ scur,
        float4* __restrict__ refp4s, int* __restrict__ ridx,
        float4* __restrict__ srcp4s, int* __restrict__ sidx) {
    int b = blockIdx.x, t = threadIdx.x;
    if (b < 64) {
        int i = b * 256 + t;
        float x = rp[i * 3 + 0], y = rp[i * 3 + 1], z = rp[i * 3 + 2];
        int c = (cell_of(z) * NC + cell_of(y)) * NC + cell_of(x);
        int pos = atomicAdd(&rcur[c], 1);
        refp4s[pos] = make_float4(x, y, z, fmaf(x, x, fmaf(y, y, z * z)));
        ridx[pos] = i;
    } else {
        int i = (b - 64) * 256 + t;
        float x = sp[i * 3 + 0], y = sp[i * 3 + 1], z = sp[i * 3 + 2];
        int c = (cell_of(z) * NC + cell_of(y)) * NC + cell_of(x);
        int pos = atomicAdd(&scur[c], 1);
        srcp4s[pos] = make_float4(x, y, z, fmaf(x, x, fmaf(y, y, z * z)));
        sidx[pos] = i;
    }
}

// ---------------- helpers ----------------
__device__ __forceinline__ float kth16_lane_min(float v, int lane) {
    #pragma unroll
    for (int k = 2; k <= 64; k <<= 1)
        #pragma unroll
        for (int j = k >> 1; j > 0; j >>= 1) {
            float o = __shfl_xor(v, j, 64);
            bool lower = (lane & j) == 0;
            bool up = (lane & k) == 0;
            float mn = fminf(v, o), mx = fmaxf(v, o);
            v = (lower == up) ? mn : mx;
        }
    return __shfl(v, 15, 64);
}

__device__ __forceinline__ void sort64_kv(float& vd, int& vi, int lane) {
    #pragma unroll
    for (int k = 2; k <= 64; k <<= 1)
        #pragma unroll
        for (int j = k >> 1; j > 0; j >>= 1) {
            float od = __shfl_xor(vd, j, 64);
            int   oi = __shfl_xor(vi, j, 64);
            bool keep_min = (((lane & j) == 0) == ((lane & k) == 0));
            bool oless = (od < vd) || (od == vd && oi < vi);
            bool take = (keep_min == oless);
            vd = take ? od : vd;
            vi = take ? oi : vi;
        }
}

// Per-src tau probe: R8's validated tau_kernel logic, verbatim semantics.
// Scan own r=1 cube (expand x2 while <16 points), round-robin lane fill;
// tau = 16th-smallest lane-min = 16 distinct real distances => sound upper
// bound on the true 16th distance (d' = |r|^2 - 2 r.s space).
__device__ __forceinline__ float probe_tau(int cx, int cy, int cz,
        float m2x, float m2y, float m2z,
        const float4* __restrict__ refp4s, const int* __restrict__ rcs, int lane) {
    const float INF = 3.0e38f;
    int r = 1;
    while (true) {
        int x0 = max(cx - r, 0), x1 = min(cx + r, NC - 1);
        int y0 = max(cy - r, 0), y1 = min(cy + r, NC - 1);
        int z0 = max(cz - r, 0), z1 = min(cz + r, NC - 1);
        float mind = INF;
        int off = 0, tot = 0;
        for (int zc = z0; zc <= z1; ++zc)
            for (int yc = y0; yc <= y1; ++yc) {
                int rb = (zc * NC + yc) * NC;
                int st = rcs[rb + x0];
                int np = rcs[rb + x1 + 1] - st;
                int k = lane - off; if (k < 0) k += 64;
                for (; k < np; k += 64) {
                    float4 rp = refp4s[st + k];
                    float d = fmaf(rp.x, m2x, rp.w);
                    d = fmaf(rp.y, m2y, d);
                    d = fmaf(rp.z, m2z, d);
                    mind = fminf(mind, d);
                }
                off = (off + np) & 63;
                tot += np;
            }
        bool full = (x0 == 0 && y0 == 0 && z0 == 0 &&
                     x1 == NC - 1 && y1 == NC - 1 && z1 == NC - 1);
        if (tot >= KNN_K || full) return kth16_lane_min(mind, lane);
        r <<= 1;
    }
}

// ---------------- K5: fused exact KNN (per-src probe + (y,z)-band + repair) + q-GEMM ----
// KNN blocks [0,KNNB): 4 waves x 4 cell-sorted srcs each.
// Probe: per-src (R8-validated). Window: union over b of z-slabs/y-band at radius
//   t_b = sqrt(tau_b+|s_b|^2)*1.0005+1.5e-3; within slab zc the y-band is ONE
//   contiguous CSR range. Ballot append (no atomics), gate d <= tau_b.
// Repair: if cnt<16 or cnt>CAP for a src, redo that src with the R3-validated
//   full-scan two-pass (full lane-min -> tau2 -> gated append). Guarantees >=16
//   real candidates and bounded counts regardless of window/probe anomalies.
// Selection: exact (d2,idx)-lex bitonic top-16 (matches jax stable top_k).
__global__ void __launch_bounds__(256) knnq_kernel(
        const float4* __restrict__ srcp4s, const int* __restrict__ sidx,
        const float4* __restrict__ refp4s, const int* __restrict__ ridx,
        const int* __restrict__ rcs,
        float* __restrict__ kd2, int* __restrict__ kidx,
        const float* __restrict__ src_feats, const float* __restrict__ wsym,
        float* __restrict__ q) {
    __shared__ __align__(16) float smem[4096];   // 16 KB both parts
    int tid = threadIdx.x;

    if (blockIdx.x < KNNB) {
        const float INF = 3.0e38f;
        int wave = tid >> 6, lane = tid & 63;
        float* cdw = smem + wave * (4 * CAP);
        int*   ciw = (int*)(smem + 2048) + wave * (4 * CAP);
        int s0 = __builtin_amdgcn_readfirstlane(blockIdx.x * 16 + wave * 4);

        float m2x[4], m2y[4], m2z[4], sn2[4], syv[4], szv[4];
        int scx[4], scy[4], scz[4];
        #pragma unroll
        for (int b = 0; b < 4; ++b) {
            float4 s4 = srcp4s[s0 + b];
            m2x[b] = -2.f * s4.x; m2y[b] = -2.f * s4.y; m2z[b] = -2.f * s4.z;
            sn2[b] = s4.w; syv[b] = s4.y; szv[b] = s4.z;
            scx[b] = cell_of(s4.x); scy[b] = cell_of(s4.y); scz[b] = cell_of(s4.z);
        }

        // ---- per-src probes (R8 semantics) ----
        float tau[4];
        #pragma unroll
        for (int b = 0; b < 4; ++b)
            tau[b] = probe_tau(scx[b], scy[b], scz[b], m2x[b], m2y[b], m2z[b],
                               refp4s, rcs, lane);

        // ---- window: union of per-src (y,z) bands, epsilon-inflated ----
        int zlo = NC - 1, zhi = 0, ylo = NC - 1, yhi = 0;
        #pragma unroll
        for (int b = 0; b < 4; ++b) {
            float t = sqrtf(fmaxf(tau[b] + sn2[b], 0.f)) * 1.0005f + 1.5e-3f;
            zlo = min(zlo, cell_of(szv[b] - t));
            zhi = max(zhi, cell_of(szv[b] + t));
            ylo = min(ylo, cell_of(syv[b] - t));
            yhi = max(yhi, cell_of(syv[b] + t));
        }

        // ---- stream per-slab contiguous y-band, ballot append ----
        int cnt[4] = {0, 0, 0, 0};
        for (int zc = zlo; zc <= zhi; ++zc) {
            int st = rcs[(zc * NC + ylo) * NC];
            int en = rcs[(zc * NC + yhi + 1) * NC];
            int iters = (en - st + 63) >> 6;
            for (int it = 0; it < iters; ++it) {
                int k = st + it * 64 + lane;
                bool inr = k < en;
                float4 rp = refp4s[inr ? k : st];
                #pragma unroll
                for (int b = 0; b < 4; ++b) {
                    float d = fmaf(rp.x, m2x[b], rp.w);
                    d = fmaf(rp.y, m2y[b], d);
                    d = fmaf(rp.z, m2z[b], d);
                    bool pred = inr && (d <= tau[b]);
                    unsigned long long m = __ballot(pred);
                    int pos = cnt[b] + (int)__popcll(m & ((1ull << lane) - 1ull));
                    if (pred && pos < CAP) {
                        cdw[b * CAP + pos] = d;
                        ciw[b * CAP + pos] = ridx[k];
                    }
                    cnt[b] += (int)__popcll(m);
                }
            }
        }

        // ---- per-src: repair (if anomalous) + selection + write ----
        #pragma unroll
        for (int b = 0; b < 4; ++b) {
            int count = cnt[b];
            if (count < KNN_K || count > CAP) {
                // R3-validated full-scan two-pass repair
                float mind = INF;
                for (int p = lane; p < M_REF; p += 64) {
                    float4 rp = refp4s[p];
                    float d = fmaf(rp.x, m2x[b], rp.w);
                    d = fmaf(rp.y, m2y[b], d);
                    d = fmaf(rp.z, m2z[b], d);
                    mind = fminf(mind, d);
                }
                float tau2 = kth16_lane_min(mind, lane);
                int c2 = 0;
                for (int it = 0; it < M_REF / 64; ++it) {
                    int p = it * 64 + lane;
                    float4 rp = refp4s[p];
                    float d = fmaf(rp.x, m2x[b], rp.w);
                    d = fmaf(rp.y, m2y[b], d);
                    d = fmaf(rp.z, m2z[b], d);
                    bool pred = (d <= tau2);
                    unsigned long long m = __ballot(pred);
                    int pos = c2 + (int)__popcll(m & ((1ull << lane) - 1ull));
                    if (pred && pos < CAP) {
                        cdw[b * CAP + pos] = d;
                        ciw[b * CAP + pos] = ridx[p];
                    }
                    c2 += (int)__popcll(m);
                }
                count = c2;
            }
            if (count > CAP) count = CAP;

            float vd = (lane < count) ? cdw[b * CAP + lane] : INF;
            int   vi = (lane < count) ? ciw[b * CAP + lane] : 0x7fffffff;
            sort64_kv(vd, vi, lane);
            int done = 64;
            while (done < count) {
                if (lane >= 16) {
                    int p = done + (lane - 16);
                    vd = (p < count) ? cdw[b * CAP + p] : INF;
                    vi = (p < count) ? ciw[b * CAP + p] : 0x7fffffff;
                }
                sort64_kv(vd, vi, lane);
                done += 48;
            }
            int orig = sidx[s0 + b];
            if (lane < KNN_K) {
                kd2[(size_t)orig * KNN_K + lane] = vd + sn2[b];
                kidx[(size_t)orig * KNN_K + lane] = min(vi, M_REF - 1);  // fault guard
            }
        }
    } else {
        // ================= q-GEMM: q = src_feats @ W_sym =================
        float (*sf)[DEMB] = (float(*)[DEMB])smem;
        int n0 = (blockIdx.x - KNNB) * 16;
        int c0 = tid & 63;
        int rg = tid >> 6;
        {
            int c = c0 * 4;
            #pragma unroll
            for (int rr = 0; rr < 4; ++rr) {
                int rw = rr * 4 + rg;
                *(float4*)&sf[rw][c] = *(const float4*)&src_feats[(size_t)(n0 + rw) * DEMB + c];
            }
        }
        __syncthreads();

        float acc[4][4];
        #pragma unroll
        for (int rr = 0; rr < 4; ++rr)
            #pragma unroll
            for (int cc = 0; cc < 4; ++cc) acc[rr][cc] = 0.f;

        for (int c4 = 0; c4 < 64; ++c4) {
            float wv[4][4];
            #pragma unroll
            for (int j = 0; j < 4; ++j)
                #pragma unroll
                for (int cc = 0; cc < 4; ++cc)
                    wv[j][cc] = wsym[(size_t)(c4 * 4 + j) * DEMB + c0 + cc * 64];
            #pragma unroll
            for (int rr = 0; rr < 4; ++rr) {
                float4 s4 = *(const float4*)&sf[rg * 4 + rr][c4 * 4];
                #pragma unroll
                for (int cc = 0; cc < 4; ++cc) {
                    float a = acc[rr][cc];
                    a = fmaf(s4.x, wv[0][cc], a);
                    a = fmaf(s4.y, wv[1][cc], a);
                    a = fmaf(s4.z, wv[2][cc], a);
                    a = fmaf(s4.w, wv[3][cc], a);
                    acc[rr][cc] = a;
                }
            }
        }
        #pragma unroll
        for (int rr = 0; rr < 4; ++rr)
            #pragma unroll
            for (int cc = 0; cc < 4; ++cc)
                q[(size_t)(n0 + rg * 4 + rr) * DEMB + (c0 + cc * 64)] = acc[rr][cc];
    }
}

// ---------------- K6: scores, softmax, corres, w ----------------
__global__ void __launch_bounds__(256) score_kernel(const float* __restrict__ q,
                                                    const float* __restrict__ ref_feats,
                                                    const float* __restrict__ ref_points,
                                                    const float* __restrict__ src_points,
                                                    const float* __restrict__ kd2,
                                                    const int* __restrict__ kidx,
                                                    float* __restrict__ out) {
    int wave = threadIdx.x >> 6;
    int lane = threadIdx.x & 63;
    int n = __builtin_amdgcn_readfirstlane(blockIdx.x * 4 + wave);

    float4 qv = *(const float4*)&q[(size_t)n * DEMB + lane * 4];

    int idx[KNN_K]; float d2[KNN_K];
    #pragma unroll
    for (int k = 0; k < KNN_K; ++k) {
        idx[k] = __builtin_amdgcn_readfirstlane(kidx[(size_t)n * KNN_K + k]);
        d2[k]  = kd2[(size_t)n * KNN_K + k];
    }

    float sc[KNN_K];
    #pragma unroll
    for (int k = 0; k < KNN_K; ++k) {
        float4 r = *(const float4*)&ref_feats[(size_t)idx[k] * DEMB + lane * 4];
        float p = fmaf(r.x, qv.x, fmaf(r.y, qv.y, fmaf(r.z, qv.z, r.w * qv.w)));
        #pragma unroll
        for (int off = 1; off < 64; off <<= 1) p += __shfl_xor(p, off, 64);
        sc[k] = p;
    }

    float tv[KNN_K];
    #pragma unroll
    for (int k = 0; k < KNN_K; ++k) {
        float wt = fmaxf(0.f, fmaf(-2.f, d2[k], 1.f));
        tv[k] = sc[k] * wt;
    }
    float m = tv[0];
    #pragma unroll
    for (int k = 1; k < KNN_K; ++k) m = fmaxf(m, tv[k]);
    float e[KNN_K], s = 0.f;
    #pragma unroll
    for (int k = 0; k < KNN_K; ++k) { e[k] = expf(tv[k] - m); s += e[k]; }

    float cxx = 0.f, cyy = 0.f, czz = 0.f;
    #pragma unroll
    for (int k = 0; k < KNN_K; ++k) {
        float rx = ref_points[idx[k] * 3 + 0];
        float ry = ref_points[idx[k] * 3 + 1];
        float rz = ref_points[idx[k] * 3 + 2];
        cxx = fmaf(e[k], rx, cxx);
        cyy = fmaf(e[k], ry, cyy);
        czz = fmaf(e[k], rz, czz);
    }
    float inv = 1.f / s;
    cxx *= inv; cyy *= inv; czz *= inv;

    if (lane == 0) {
        float ssx = src_points[n * 3 + 0];
        float ssy = src_points[n * 3 + 1];
        float ssz = src_points[n * 3 + 2];
        float dx = ssx - cxx, dy = ssy - cyy, dz = ssz - czz;
        float dist = sqrtf(fmaf(dx, dx, fmaf(dy, dy, dz * dz)));
        float w = fmaxf(0.f, fmaf(-2.f, dist, 1.f));
        out[(size_t)n * 3 + 0] = cxx;
        out[(size_t)n * 3 + 1] = cyy;
        out[(size_t)n * 3 + 2] = czz;
        out[(size_t)N_SRC * 3 + n] = w;
    }
}

extern "C" void kernel_launch(void* const* d_in, const int* in_sizes, int n_in,
                              void* d_out, int out_size, void* d_ws, size_t ws_size,
                              hipStream_t stream) {
    const float* ref_points = (const float*)d_in[0];
    const float* src_points = (const float*)d_in[1];
    const float* ref_feats  = (const float*)d_in[2];
    const float* src_feats  = (const float*)d_in[3];
    const float* W          = (const float*)d_in[4];
    float* out = (float*)d_out;

    char* ws = (char*)d_ws;
    float4* refp4s = (float4*)ws;         ws += (size_t)M_REF * 16;
    float4* srcp4s = (float4*)ws;         ws += (size_t)N_SRC * 16;
    float*  q      = (float*)ws;          ws += (size_t)N_SRC * DEMB * 4;
    float*  wsym   = (float*)ws;          ws += (size_t)DEMB * DEMB * 4;
    float*  kd2    = (float*)ws;          ws += (size_t)N_SRC * KNN_K * 4;
    int*    kidx   = (int*)ws;            ws += (size_t)N_SRC * KNN_K * 4;
    int*    ridx   = (int*)ws;            ws += (size_t)M_REF * 4;
    int*    sidx   = (int*)ws;            ws += (size_t)N_SRC * 4;
    int*    rcs    = (int*)ws;            ws += (size_t)(NCELLS + 8) * 4;
    int*    scs    = (int*)ws;            ws += (size_t)(NCELLS + 8) * 4;
    int*    rcur   = (int*)ws;            ws += (size_t)NCELLS * 4;
    int*    scur   = (int*)ws;

    setup_kernel<<<512, 256, 0, stream>>>(rcur, scur, W, wsym);
    hist_kernel<<<128, 256, 0, stream>>>(ref_points, src_points, rcur, scur);
    scan_kernel<<<2, 1024, 0, stream>>>(rcur, rcs, scur, scs);
    scatter_kernel<<<128, 256, 0, stream>>>(ref_points, src_points, rcur, scur,
                                            refp4s, ridx, srcp4s, sidx);
    knnq_kernel<<<KNNB + QB, 256, 0, stream>>>(srcp4s, sidx, refp4s, ridx, rcs,
                                               kd2, kidx, src_feats, wsym, q);
    score_kernel<<<N_SRC / 4, 256, 0, stream>>>(q, ref_feats, ref_points, src_points,
                                                kd2, kidx, out);
}